// Round 5
// baseline (289.654 us; speedup 1.0000x reference)
//
#include <hip/hip_runtime.h>

// out[b,h,w,d,c] = in[b,h,w,d] * u[d,c],  u = beta^2 / rowsum(beta^2)
// in: [16,160,320,32] fp32 (104.9 MB), beta: [32,2], out: 2x in (209.7 MB).
// Traffic floor 314.6 MB -> ~48-55 us mixed-stream at ~6 TB/s.
//
// R7: R5 layout (8B nt load -> 16B nt store, dense per instruction on both
// sides) + grid 4096 (full TLP: 1M threads -- R6's grid-2048 halved TLP
// and regressed +12 us). New, isolated lever: uniform 12-iter fast path
// with unroll 4 (4 independent load/store pairs in flight per wave),
// remainder loop covers the extra half-iteration (12.5 avg trips).
// VGPR budget ~56 < 64 -> still 32 waves/CU.

typedef float f32x2 __attribute__((ext_vector_type(2)));
typedef float f32x4 __attribute__((ext_vector_type(4)));

__global__ __launch_bounds__(256) void DS2_87582973100612_kernel(
    const f32x2* __restrict__ in2,
    const float* __restrict__ beta,
    f32x4*       __restrict__ out4,
    int n_out4)
{
    const int gid    = blockIdx.x * blockDim.x + threadIdx.x;
    const int stride = gridDim.x * blockDim.x; // 1,048,576: mult of 16 -> d0 loop-invariant

    // Output float4 o covers (d0, d1=d0+1) with d0 = (2*o) & 31 (even).
    const int d0 = (2 * gid) & 31;
    const int d1 = d0 + 1;

    const float a0 = beta[2 * d0], a1 = beta[2 * d0 + 1];
    const float b0 = beta[2 * d1], b1 = beta[2 * d1 + 1];
    const float sa0 = a0 * a0, sa1 = a1 * a1;
    const float sb0 = b0 * b0, sb1 = b1 * b1;
    const float inva = 1.0f / (sa0 + sa1);
    const float invb = 1.0f / (sb0 + sb1);
    const float u00 = sa0 * inva, u01 = sa1 * inva; // u[d0, 0], u[d0, 1]
    const float u10 = sb0 * invb, u11 = sb1 * invb; // u[d1, 0], u[d1, 1]

    // Uniform fast path: iters = floor(n_out4 / stride) = 12 for the bench
    // shape; unroll 4 for ILP. Remainder loop does the final half-iteration.
    const int iters = n_out4 / stride;
    int o = gid;
    #pragma unroll 4
    for (int k = 0; k < iters; ++k, o += stride) {
        const f32x2 x = __builtin_nontemporal_load(&in2[o]);
        f32x4 y;
        y.x = x.x * u00;
        y.y = x.x * u01;
        y.z = x.y * u10;
        y.w = x.y * u11;
        __builtin_nontemporal_store(y, &out4[o]);
    }
    for (; o < n_out4; o += stride) {
        const f32x2 x = __builtin_nontemporal_load(&in2[o]);
        f32x4 y;
        y.x = x.x * u00;
        y.y = x.x * u01;
        y.z = x.y * u10;
        y.w = x.y * u11;
        __builtin_nontemporal_store(y, &out4[o]);
    }
}

extern "C" void kernel_launch(void* const* d_in, const int* in_sizes, int n_in,
                              void* d_out, int out_size, void* d_ws, size_t ws_size,
                              hipStream_t stream) {
    const float* in   = (const float*)d_in[0];
    const float* beta = (const float*)d_in[1];
    float* out        = (float*)d_out;

    const int n_out4 = out_size / 4;  // 13,107,200

    const int block = 256;
    const int grid  = 4096;           // 1,048,576 threads; stride mult of 16

    DS2_87582973100612_kernel<<<grid, block, 0, stream>>>(
        (const f32x2*)in, beta, (f32x4*)out, n_out4);
}

// Round 6
// 274.304 us; speedup vs baseline: 1.0560x; 1.0560x over previous
//
#include <hip/hip_runtime.h>

// out[b,h,w,d,c] = in[b,h,w,d] * u[d,c],  u = beta^2 / rowsum(beta^2)
// in: [16,160,320,32] fp32 (104.9 MB), beta: [32,2], out: 2x in (209.7 MB).
// Traffic floor 314.6 MB -> ~48-55 us mixed-stream at ~6 TB/s.
//
// R8 = R5 champion restored (276.4 us). Lever history (all isolated):
//   - R4: 16B loads + stride-2 stores  -> +13 us (store density dominates)
//   - R5: dense-dense + nt hints       -> -3.5 us vs R0 (best: 276.4)
//   - R6: grid 2048 + unroll 5         -> +12 us (TLP halved; latency exposed)
//   - R7: unroll 4 @ grid 4096         -> +13 us (ILP batching serializes
//          vmcnt drains; simple loop + 8 waves/SIMD TLP hides latency better)
// Layout: thread o does an 8B nt float2 load -> 16B nt float4 store; both
// sides 100% line-dense per instruction. d0 loop-invariant (stride % 16 == 0).

typedef float f32x2 __attribute__((ext_vector_type(2)));
typedef float f32x4 __attribute__((ext_vector_type(4)));

__global__ __launch_bounds__(256) void DS2_87582973100612_kernel(
    const f32x2* __restrict__ in2,
    const float* __restrict__ beta,
    f32x4*       __restrict__ out4,
    int n_out4)
{
    const int gid    = blockIdx.x * blockDim.x + threadIdx.x;
    const int stride = gridDim.x * blockDim.x; // multiple of 16 -> d0 loop-invariant

    // Output float4 o covers (d0, d1=d0+1) with d0 = (2*o) & 31 (even).
    const int d0 = (2 * gid) & 31;
    const int d1 = d0 + 1;

    const float a0 = beta[2 * d0], a1 = beta[2 * d0 + 1];
    const float b0 = beta[2 * d1], b1 = beta[2 * d1 + 1];
    const float sa0 = a0 * a0, sa1 = a1 * a1;
    const float sb0 = b0 * b0, sb1 = b1 * b1;
    const float inva = 1.0f / (sa0 + sa1);
    const float invb = 1.0f / (sb0 + sb1);
    const float u00 = sa0 * inva, u01 = sa1 * inva; // u[d0, 0], u[d0, 1]
    const float u10 = sb0 * invb, u11 = sb1 * invb; // u[d1, 0], u[d1, 1]

    for (int o = gid; o < n_out4; o += stride) {
        const f32x2 x = __builtin_nontemporal_load(&in2[o]);
        f32x4 y;
        y.x = x.x * u00;
        y.y = x.x * u01;
        y.z = x.y * u10;
        y.w = x.y * u11;
        __builtin_nontemporal_store(y, &out4[o]);
    }
}

extern "C" void kernel_launch(void* const* d_in, const int* in_sizes, int n_in,
                              void* d_out, int out_size, void* d_ws, size_t ws_size,
                              hipStream_t stream) {
    const float* in   = (const float*)d_in[0];
    const float* beta = (const float*)d_in[1];
    float* out        = (float*)d_out;

    const int n_out4 = out_size / 4;  // 13,107,200

    const int block = 256;
    const int grid  = 4096;           // 1,048,576 threads; stride mult of 16

    DS2_87582973100612_kernel<<<grid, block, 0, stream>>>(
        (const f32x2*)in, beta, (f32x4*)out, n_out4);
}